// Round 1
// baseline (2099.085 us; speedup 1.0000x reference)
//
#include <hip/hip_runtime.h>
#include <cstddef>

#define T_TOK 4096
#define H_DIM 2048
#define E_NUM 8
#define I_DIM 1024
#define TWO_I 2048

// -------- workspace layout (bytes) --------
// scale   float[4096]        @ 0
// counts  int[8]             @ 32768
// buckets int[8*4096]        @ 33280
// act     float[4096*1024]   @ 262144   (16.8 MB)
#define WS_SCALE_OFF   0
#define WS_COUNTS_OFF  32768
#define WS_BUCKETS_OFF 33280
#define WS_ACT_OFF     262144

// ---------------- router ----------------
// one wave per token: 8 dot products of length H, argmax (first-max), sigmoid
__global__ __launch_bounds__(256) void router_kernel(
    const float* __restrict__ x, const float* __restrict__ gw,
    float* __restrict__ scale, int* __restrict__ counts, int* __restrict__ buckets)
{
    const int wid  = threadIdx.x >> 6;
    const int lane = threadIdx.x & 63;
    const int t = blockIdx.x * 4 + wid;
    if (t >= T_TOK) return;

    float acc[E_NUM];
#pragma unroll
    for (int e = 0; e < E_NUM; ++e) acc[e] = 0.f;

    const float* xr = x + (size_t)t * H_DIM;
    for (int h = lane; h < H_DIM; h += 64) {
        float xv = xr[h];
#pragma unroll
        for (int e = 0; e < E_NUM; ++e) acc[e] = fmaf(xv, gw[e * H_DIM + h], acc[e]);
    }
#pragma unroll
    for (int e = 0; e < E_NUM; ++e) {
        float v = acc[e];
#pragma unroll
        for (int off = 32; off > 0; off >>= 1) v += __shfl_xor(v, off);
        acc[e] = v;
    }
    if (lane == 0) {
        int best = 0; float bv = acc[0];
#pragma unroll
        for (int e = 1; e < E_NUM; ++e) { if (acc[e] > bv) { bv = acc[e]; best = e; } }
        scale[t] = 1.f / (1.f + expf(-bv));
        int pos = atomicAdd(&counts[best], 1);
        buckets[best * T_TOK + pos] = t;
    }
}

// ---------------- grouped GEMM1 + SwiGLU ----------------
// tile: 64 tokens x 128 f-cols (of I), K=H in steps of 16.
// computes up (cols f) and gate (cols f+I) simultaneously, writes act = up*silu(gate)
__global__ __launch_bounds__(256) void gemm1_act_kernel(
    const float* __restrict__ x, const float* __restrict__ gup,
    const float* __restrict__ scale, const int* __restrict__ counts,
    const int* __restrict__ buckets, float* __restrict__ act)
{
    __shared__ float sA[16][68];    // [k][token] (+4 pad)
    __shared__ float sWu[16][132];  // [k][f]     (+4 pad)
    __shared__ float sWg[16][132];

    const int tid = threadIdx.x;
    const int e   = blockIdx.x >> 6;
    const int t0  = (blockIdx.x & 63) << 6;
    const int cnt = counts[e];
    if (t0 >= cnt) return;
    const int f0 = blockIdx.y << 7;     // 0..896

    // A staging mapping: row = tid/4, k-quad = (tid%4)*4
    const int ar  = tid >> 2;
    const int akq = (tid & 3) << 2;
    const int aidx = t0 + ar;
    const int atok = (aidx < cnt) ? buckets[e * T_TOK + aidx] : -1;
    const float asc = (atok >= 0) ? scale[atok] : 0.f;
    const float* arow = x + (size_t)(atok >= 0 ? atok : 0) * H_DIM;

    // W staging mapping: row = tid/16, f-oct = (tid%16)*8
    const int wr = tid >> 4;
    const int wf = (tid & 15) << 3;
    const float* gup_u = gup + (size_t)e * H_DIM * TWO_I + (f0 + wf);
    const float* gup_g = gup_u + I_DIM;

    // compute mapping: 4 tokens x 8 f per thread
    const int tt = tid >> 4;    // 0..15
    const int tf = tid & 15;    // 0..15

    float accU[4][8], accG[4][8];
#pragma unroll
    for (int i = 0; i < 4; ++i)
#pragma unroll
        for (int j = 0; j < 8; ++j) { accU[i][j] = 0.f; accG[i][j] = 0.f; }

    for (int kb = 0; kb < H_DIM; kb += 16) {
        float4 av = make_float4(0.f, 0.f, 0.f, 0.f);
        if (atok >= 0) av = *(const float4*)(arow + kb + akq);
        sA[akq + 0][ar] = av.x * asc;
        sA[akq + 1][ar] = av.y * asc;
        sA[akq + 2][ar] = av.z * asc;
        sA[akq + 3][ar] = av.w * asc;

        const float* pu = gup_u + (size_t)(kb + wr) * TWO_I;
        const float* pg = gup_g + (size_t)(kb + wr) * TWO_I;
        float4 u0 = *(const float4*)(pu);
        float4 u1 = *(const float4*)(pu + 4);
        float4 g0 = *(const float4*)(pg);
        float4 g1 = *(const float4*)(pg + 4);
        *(float4*)&sWu[wr][wf]     = u0;
        *(float4*)&sWu[wr][wf + 4] = u1;
        *(float4*)&sWg[wr][wf]     = g0;
        *(float4*)&sWg[wr][wf + 4] = g1;
        __syncthreads();

#pragma unroll
        for (int k = 0; k < 16; ++k) {
            float4 a4  = *(const float4*)&sA[k][tt << 2];
            float4 bu0 = *(const float4*)&sWu[k][tf << 3];
            float4 bu1 = *(const float4*)&sWu[k][(tf << 3) + 4];
            float4 bg0 = *(const float4*)&sWg[k][tf << 3];
            float4 bg1 = *(const float4*)&sWg[k][(tf << 3) + 4];
            float aa[4] = {a4.x, a4.y, a4.z, a4.w};
            float bu[8] = {bu0.x, bu0.y, bu0.z, bu0.w, bu1.x, bu1.y, bu1.z, bu1.w};
            float bg[8] = {bg0.x, bg0.y, bg0.z, bg0.w, bg1.x, bg1.y, bg1.z, bg1.w};
#pragma unroll
            for (int i = 0; i < 4; ++i)
#pragma unroll
                for (int j = 0; j < 8; ++j) {
                    accU[i][j] = fmaf(aa[i], bu[j], accU[i][j]);
                    accG[i][j] = fmaf(aa[i], bg[j], accG[i][j]);
                }
        }
        __syncthreads();
    }

    // epilogue: act = up * gate * sigmoid(gate)
#pragma unroll
    for (int i = 0; i < 4; ++i) {
        int idx = t0 + (tt << 2) + i;
        if (idx >= cnt) continue;
        int tk = buckets[e * T_TOK + idx];
        float vals[8];
#pragma unroll
        for (int j = 0; j < 8; ++j) {
            float g = accG[i][j];
            float s = 1.f / (1.f + expf(-g));
            vals[j] = accU[i][j] * g * s;
        }
        float* orow = act + (size_t)tk * I_DIM + f0 + (tf << 3);
        *(float4*)orow       = make_float4(vals[0], vals[1], vals[2], vals[3]);
        *((float4*)orow + 1) = make_float4(vals[4], vals[5], vals[6], vals[7]);
    }
}

// ---------------- grouped GEMM2 (act @ down_w -> out rows) ----------------
__global__ __launch_bounds__(256) void gemm2_kernel(
    const float* __restrict__ act, const float* __restrict__ dw,
    const int* __restrict__ counts, const int* __restrict__ buckets,
    float* __restrict__ out)
{
    __shared__ float sA[16][68];
    __shared__ float sW[16][132];

    const int tid = threadIdx.x;
    const int e   = blockIdx.x >> 6;
    const int t0  = (blockIdx.x & 63) << 6;
    const int cnt = counts[e];
    if (t0 >= cnt) return;
    const int f0 = blockIdx.y << 7;   // 0..1920 over H

    const int ar  = tid >> 2;
    const int akq = (tid & 3) << 2;
    const int aidx = t0 + ar;
    const int atok = (aidx < cnt) ? buckets[e * T_TOK + aidx] : -1;
    const float* arow = act + (size_t)(atok >= 0 ? atok : 0) * I_DIM;

    const int wr = tid >> 4;
    const int wf = (tid & 15) << 3;
    const float* dwb = dw + (size_t)e * I_DIM * H_DIM + (f0 + wf);

    const int tt = tid >> 4;
    const int tf = tid & 15;

    float acc[4][8];
#pragma unroll
    for (int i = 0; i < 4; ++i)
#pragma unroll
        for (int j = 0; j < 8; ++j) acc[i][j] = 0.f;

    for (int kb = 0; kb < I_DIM; kb += 16) {
        float4 av = make_float4(0.f, 0.f, 0.f, 0.f);
        if (atok >= 0) av = *(const float4*)(arow + kb + akq);
        sA[akq + 0][ar] = av.x;
        sA[akq + 1][ar] = av.y;
        sA[akq + 2][ar] = av.z;
        sA[akq + 3][ar] = av.w;

        const float* pw = dwb + (size_t)(kb + wr) * H_DIM;
        float4 w0 = *(const float4*)(pw);
        float4 w1 = *(const float4*)(pw + 4);
        *(float4*)&sW[wr][wf]     = w0;
        *(float4*)&sW[wr][wf + 4] = w1;
        __syncthreads();

#pragma unroll
        for (int k = 0; k < 16; ++k) {
            float4 a4 = *(const float4*)&sA[k][tt << 2];
            float4 b0 = *(const float4*)&sW[k][tf << 3];
            float4 b1 = *(const float4*)&sW[k][(tf << 3) + 4];
            float aa[4] = {a4.x, a4.y, a4.z, a4.w};
            float bb[8] = {b0.x, b0.y, b0.z, b0.w, b1.x, b1.y, b1.z, b1.w};
#pragma unroll
            for (int i = 0; i < 4; ++i)
#pragma unroll
                for (int j = 0; j < 8; ++j)
                    acc[i][j] = fmaf(aa[i], bb[j], acc[i][j]);
        }
        __syncthreads();
    }

#pragma unroll
    for (int i = 0; i < 4; ++i) {
        int idx = t0 + (tt << 2) + i;
        if (idx >= cnt) continue;
        int tk = buckets[e * T_TOK + idx];
        float* orow = out + (size_t)tk * H_DIM + f0 + (tf << 3);
        *(float4*)orow       = make_float4(acc[i][0], acc[i][1], acc[i][2], acc[i][3]);
        *((float4*)orow + 1) = make_float4(acc[i][4], acc[i][5], acc[i][6], acc[i][7]);
    }
}

extern "C" void kernel_launch(void* const* d_in, const int* in_sizes, int n_in,
                              void* d_out, int out_size, void* d_ws, size_t ws_size,
                              hipStream_t stream) {
    const float* x   = (const float*)d_in[0];
    const float* gw  = (const float*)d_in[1];
    const float* gup = (const float*)d_in[2];
    const float* dw  = (const float*)d_in[3];
    float* out = (float*)d_out;

    char* ws = (char*)d_ws;
    float* scale  = (float*)(ws + WS_SCALE_OFF);
    int*   counts = (int*)(ws + WS_COUNTS_OFF);
    int*   buckets= (int*)(ws + WS_BUCKETS_OFF);
    float* act    = (float*)(ws + WS_ACT_OFF);

    hipMemsetAsync(counts, 0, E_NUM * sizeof(int), stream);

    router_kernel<<<T_TOK / 4, 256, 0, stream>>>(x, gw, scale, counts, buckets);

    dim3 g1(E_NUM * (T_TOK / 64), I_DIM / 128);
    gemm1_act_kernel<<<g1, 256, 0, stream>>>(x, gup, scale, counts, buckets, act);

    dim3 g2(E_NUM * (T_TOK / 64), H_DIM / 128);
    gemm2_kernel<<<g2, 256, 0, stream>>>(act, dw, counts, buckets, out);
}

// Round 2
// 635.187 us; speedup vs baseline: 3.3047x; 3.3047x over previous
//
#include <hip/hip_runtime.h>
#include <hip/hip_bf16.h>
#include <cstddef>
#include <cstdint>

#define T_TOK 4096
#define H_DIM 2048
#define E_NUM 8
#define I_DIM 1024
#define TWO_I 2048

typedef __attribute__((ext_vector_type(8))) short bf16x8;
typedef __attribute__((ext_vector_type(4))) float f32x4;
typedef __attribute__((ext_vector_type(4))) int   i32x4;

// -------- workspace layout (bytes) --------
#define WS_SCALE    0               // float[4096]
#define WS_COUNTS   16384           // int[8]
#define WS_BUCKETS  16512           // int[8*4096] -> ends 147584
#define WS_ACT_OLD  262144          // float[4096*1024] (fallback path)
#define WS_XS       (1u<<20)        // bf16[4096*2048]  = 16.8 MB -> ends ~17.8M
#define WS_ACT      (18u<<20)       // bf16[4096*1024]  =  8.4 MB -> ends ~27.3M
#define WS_W1T      (28u<<20)       // bf16[8][2048][2048] = 67.1 MB -> ends ~95.1M
#define WS_W2T      (96u<<20)       // bf16[8][2048][1024] = 33.6 MB -> ends 128M
#define WS_NEED_FAST 134217728ull

__device__ __forceinline__ short f2bf(float f) {
    uint32_t u = __builtin_bit_cast(uint32_t, f);
    u += 0x7fffu + ((u >> 16) & 1u);
    return (short)(u >> 16);
}

__device__ __forceinline__ void gload16(const void* g, void* l) {
    __builtin_amdgcn_global_load_lds(
        (const __attribute__((address_space(1))) void*)g,
        (__attribute__((address_space(3))) void*)l, 16, 0, 0);
}

// ---------------- router ----------------
__global__ __launch_bounds__(256) void router_kernel(
    const float* __restrict__ x, const float* __restrict__ gw,
    float* __restrict__ scale, int* __restrict__ counts, int* __restrict__ buckets)
{
    const int wid  = threadIdx.x >> 6;
    const int lane = threadIdx.x & 63;
    const int t = blockIdx.x * 4 + wid;
    if (t >= T_TOK) return;

    float acc[E_NUM];
#pragma unroll
    for (int e = 0; e < E_NUM; ++e) acc[e] = 0.f;

    const float* xr = x + (size_t)t * H_DIM;
    for (int h = lane; h < H_DIM; h += 64) {
        float xv = xr[h];
#pragma unroll
        for (int e = 0; e < E_NUM; ++e) acc[e] = fmaf(xv, gw[e * H_DIM + h], acc[e]);
    }
#pragma unroll
    for (int e = 0; e < E_NUM; ++e) {
        float v = acc[e];
#pragma unroll
        for (int off = 32; off > 0; off >>= 1) v += __shfl_xor(v, off);
        acc[e] = v;
    }
    if (lane == 0) {
        int best = 0; float bv = acc[0];
#pragma unroll
        for (int e = 1; e < E_NUM; ++e) { if (acc[e] > bv) { bv = acc[e]; best = e; } }
        scale[t] = 1.f / (1.f + expf(-bv));
        int pos = atomicAdd(&counts[best], 1);
        buckets[best * T_TOK + pos] = t;
    }
}

// ---------------- xs = bf16(scale * x) ----------------
__global__ __launch_bounds__(256) void xs_kernel(
    const float* __restrict__ x, const float* __restrict__ scale,
    short* __restrict__ xs)
{
    const int i = blockIdx.x * 256 + threadIdx.x;
    const int base = i * 8;
    const float sc = scale[base >> 11];
    float4 a = *(const float4*)(x + base);
    float4 b = *(const float4*)(x + base + 4);
    short o[8] __attribute__((aligned(16)));
    o[0] = f2bf(a.x * sc); o[1] = f2bf(a.y * sc);
    o[2] = f2bf(a.z * sc); o[3] = f2bf(a.w * sc);
    o[4] = f2bf(b.x * sc); o[5] = f2bf(b.y * sc);
    o[6] = f2bf(b.z * sc); o[7] = f2bf(b.w * sc);
    *(i32x4*)(xs + base) = *(const i32x4*)o;
}

// ---------------- weight transpose + bf16 convert ----------------
// src: [E][K][N] f32  ->  dst: [E][N][K] bf16
__global__ __launch_bounds__(256) void transpose_cvt_kernel(
    const float* __restrict__ src, short* __restrict__ dst, int K, int N)
{
    __shared__ float s[64][65];
    const int e  = blockIdx.z;
    const int k0 = blockIdx.x * 64;
    const int n0 = blockIdx.y * 64;
    const int t  = threadIdx.x;

    const float* S = src + ((size_t)e * K + k0) * N + n0;
    const int kr = t >> 4, nc = (t & 15) * 4;
#pragma unroll
    for (int i = 0; i < 4; ++i) {
        float4 v = *(const float4*)(S + (size_t)(kr + i * 16) * N + nc);
        s[kr + i * 16][nc + 0] = v.x;
        s[kr + i * 16][nc + 1] = v.y;
        s[kr + i * 16][nc + 2] = v.z;
        s[kr + i * 16][nc + 3] = v.w;
    }
    __syncthreads();

    const int nr = t >> 2, kc = (t & 3) * 16;
    short tmp[16] __attribute__((aligned(16)));
#pragma unroll
    for (int j = 0; j < 16; ++j) tmp[j] = f2bf(s[kc + j][nr]);
    short* D = dst + ((size_t)e * N + n0 + nr) * K + k0 + kc;
    *(i32x4*)D       = *(const i32x4*)tmp;
    *(i32x4*)(D + 8) = *(const i32x4*)(tmp + 8);
}

// ---------------- grouped MFMA GEMM1 + SwiGLU ----------------
// A = xs (bf16, gathered token rows), B = W1t[e] rows {f0..f0+63, 1024+f0..1024+f0+63}
// tile 128x128, BK=32, 4 waves, wave = 32 rows x 128 cols (2 m-frags x 8 n-frags)
__global__ __launch_bounds__(256) void gemm1_mfma_kernel(
    const short* __restrict__ xs, const short* __restrict__ w1t,
    const int* __restrict__ counts, const int* __restrict__ buckets,
    __hip_bfloat16* __restrict__ act)
{
    __shared__ short sA[128 * 32];
    __shared__ short sB[128 * 32];
    __shared__ int   sTok[128];

    const int tid  = threadIdx.x;
    const int e    = blockIdx.x >> 5;
    const int tile = blockIdx.x & 31;
    const int t0   = tile << 7;
    const int cnt  = counts[e];
    if (t0 >= cnt) return;
    const int f0 = blockIdx.y << 6;   // 0..960

    if (tid < 128) {
        int idx = t0 + tid;
        if (idx >= cnt) idx = cnt - 1;
        sTok[tid] = buckets[e * T_TOK + idx];
    }
    __syncthreads();

    const int lane = tid & 63;
    const int w    = tid >> 6;
    const int g    = lane & 3;        // 16B slot within 64B row
    const int lr   = lane >> 2;       // row within 16-row chunk

    // staging: wave w handles chunks {2w, 2w+1} of A and of B (each chunk = 16 rows = 1KB)
    const int rA0 = (2 * w) * 16 + lr, rA1 = rA0 + 16;
    const short* srcA0 = xs + (size_t)sTok[rA0] * H_DIM + g * 8;
    const short* srcA1 = xs + (size_t)sTok[rA1] * H_DIM + g * 8;
    short* dstA0 = sA + (2 * w) * 512;
    short* dstA1 = sA + (2 * w + 1) * 512;

    const int rB0 = rA0, rB1 = rA1;
    const int n0r = (rB0 < 64) ? (f0 + rB0) : (I_DIM + f0 + (rB0 & 63));
    const int n1r = (rB1 < 64) ? (f0 + rB1) : (I_DIM + f0 + (rB1 & 63));
    const short* srcB0 = w1t + ((size_t)e * TWO_I + n0r) * H_DIM + g * 8;
    const short* srcB1 = w1t + ((size_t)e * TWO_I + n1r) * H_DIM + g * 8;
    short* dstB0 = sB + (2 * w) * 512;
    short* dstB1 = sB + (2 * w + 1) * 512;

    // fragment read pointers (fixed across K since LDS rewritten in place)
    const int lm  = lane & 15;
    const int lg8 = (lane >> 4) * 8;
    const short* pA0 = sA + (w * 32 + lm) * 32 + lg8;        // mi=0
    const short* pA1 = pA0 + 16 * 32;                        // mi=1
    const short* pB  = sB + lm * 32 + lg8;                   // + nf*16*32

    f32x4 acc[2][8];
#pragma unroll
    for (int i = 0; i < 2; ++i)
#pragma unroll
        for (int j = 0; j < 8; ++j) acc[i][j] = (f32x4){0.f, 0.f, 0.f, 0.f};

    for (int kb = 0; kb < H_DIM; kb += 32) {
        gload16(srcA0 + kb, dstA0);
        gload16(srcA1 + kb, dstA1);
        gload16(srcB0 + kb, dstB0);
        gload16(srcB1 + kb, dstB1);
        __syncthreads();   // compiler drains vmcnt before s_barrier

        bf16x8 a0 = *(const bf16x8*)pA0;
        bf16x8 a1 = *(const bf16x8*)pA1;
#pragma unroll
        for (int nf = 0; nf < 8; ++nf) {
            bf16x8 b = *(const bf16x8*)(pB + nf * 16 * 32);
            acc[0][nf] = __builtin_amdgcn_mfma_f32_16x16x32_bf16(a0, b, acc[0][nf], 0, 0, 0);
            acc[1][nf] = __builtin_amdgcn_mfma_f32_16x16x32_bf16(a1, b, acc[1][nf], 0, 0, 0);
        }
        __syncthreads();
    }

    // epilogue: act = up * gate * sigmoid(gate); rows = w*32 + mi*16 + (lane>>4)*4 + r
    const int rbase = w * 32 + (lane >> 4) * 4;
#pragma unroll
    for (int mi = 0; mi < 2; ++mi) {
#pragma unroll
        for (int r = 0; r < 4; ++r) {
            const int row = rbase + mi * 16 + r;
            if (t0 + row >= cnt) continue;
            const int tok = sTok[row];
            __hip_bfloat16* orow = act + (size_t)tok * I_DIM + f0 + lm;
#pragma unroll
            for (int nf = 0; nf < 4; ++nf) {
                float up = acc[mi][nf][r];
                float gt = acc[mi][nf + 4][r];
                float v  = up * gt / (1.f + expf(-gt));
                short b  = f2bf(v);
                orow[nf * 16] = *(const __hip_bfloat16*)&b;
            }
        }
    }
}

// ---------------- grouped MFMA GEMM2 ----------------
// A = act (bf16, gathered rows, K=I), B = W2t[e] rows h0..h0+127 (K=I)
__global__ __launch_bounds__(256) void gemm2_mfma_kernel(
    const __hip_bfloat16* __restrict__ act, const short* __restrict__ w2t,
    const int* __restrict__ counts, const int* __restrict__ buckets,
    float* __restrict__ out)
{
    __shared__ short sA[128 * 32];
    __shared__ short sB[128 * 32];
    __shared__ int   sTok[128];

    const int tid  = threadIdx.x;
    const int e    = blockIdx.x >> 5;
    const int tile = blockIdx.x & 31;
    const int t0   = tile << 7;
    const int cnt  = counts[e];
    if (t0 >= cnt) return;
    const int h0 = blockIdx.y << 7;   // 0..1920

    if (tid < 128) {
        int idx = t0 + tid;
        if (idx >= cnt) idx = cnt - 1;
        sTok[tid] = buckets[e * T_TOK + idx];
    }
    __syncthreads();

    const int lane = tid & 63;
    const int w    = tid >> 6;
    const int g    = lane & 3;
    const int lr   = lane >> 2;

    const int rA0 = (2 * w) * 16 + lr, rA1 = rA0 + 16;
    const short* srcA0 = (const short*)act + (size_t)sTok[rA0] * I_DIM + g * 8;
    const short* srcA1 = (const short*)act + (size_t)sTok[rA1] * I_DIM + g * 8;
    short* dstA0 = sA + (2 * w) * 512;
    short* dstA1 = sA + (2 * w + 1) * 512;

    const short* srcB0 = w2t + ((size_t)e * H_DIM + h0 + rA0) * I_DIM + g * 8;
    const short* srcB1 = w2t + ((size_t)e * H_DIM + h0 + rA1) * I_DIM + g * 8;
    short* dstB0 = sB + (2 * w) * 512;
    short* dstB1 = sB + (2 * w + 1) * 512;

    const int lm  = lane & 15;
    const int lg8 = (lane >> 4) * 8;
    const short* pA0 = sA + (w * 32 + lm) * 32 + lg8;
    const short* pA1 = pA0 + 16 * 32;
    const short* pB  = sB + lm * 32 + lg8;

    f32x4 acc[2][8];
#pragma unroll
    for (int i = 0; i < 2; ++i)
#pragma unroll
        for (int j = 0; j < 8; ++j) acc[i][j] = (f32x4){0.f, 0.f, 0.f, 0.f};

    for (int kb = 0; kb < I_DIM; kb += 32) {
        gload16(srcA0 + kb, dstA0);
        gload16(srcA1 + kb, dstA1);
        gload16(srcB0 + kb, dstB0);
        gload16(srcB1 + kb, dstB1);
        __syncthreads();

        bf16x8 a0 = *(const bf16x8*)pA0;
        bf16x8 a1 = *(const bf16x8*)pA1;
#pragma unroll
        for (int nf = 0; nf < 8; ++nf) {
            bf16x8 b = *(const bf16x8*)(pB + nf * 16 * 32);
            acc[0][nf] = __builtin_amdgcn_mfma_f32_16x16x32_bf16(a0, b, acc[0][nf], 0, 0, 0);
            acc[1][nf] = __builtin_amdgcn_mfma_f32_16x16x32_bf16(a1, b, acc[1][nf], 0, 0, 0);
        }
        __syncthreads();
    }

    const int rbase = w * 32 + (lane >> 4) * 4;
#pragma unroll
    for (int mi = 0; mi < 2; ++mi) {
#pragma unroll
        for (int r = 0; r < 4; ++r) {
            const int row = rbase + mi * 16 + r;
            if (t0 + row >= cnt) continue;
            const int tok = sTok[row];
            float* orow = out + (size_t)tok * H_DIM + h0 + lm;
#pragma unroll
            for (int nf = 0; nf < 8; ++nf) orow[nf * 16] = acc[mi][nf][r];
        }
    }
}

// ================= fallback fp32 SIMT path (round-1, proven) =================
__global__ __launch_bounds__(256) void gemm1_act_kernel(
    const float* __restrict__ x, const float* __restrict__ gup,
    const float* __restrict__ scale, const int* __restrict__ counts,
    const int* __restrict__ buckets, float* __restrict__ act)
{
    __shared__ float sA[16][68];
    __shared__ float sWu[16][132];
    __shared__ float sWg[16][132];

    const int tid = threadIdx.x;
    const int e   = blockIdx.x >> 6;
    const int t0  = (blockIdx.x & 63) << 6;
    const int cnt = counts[e];
    if (t0 >= cnt) return;
    const int f0 = blockIdx.y << 7;

    const int ar  = tid >> 2;
    const int akq = (tid & 3) << 2;
    const int aidx = t0 + ar;
    const int atok = (aidx < cnt) ? buckets[e * T_TOK + aidx] : -1;
    const float asc = (atok >= 0) ? scale[atok] : 0.f;
    const float* arow = x + (size_t)(atok >= 0 ? atok : 0) * H_DIM;

    const int wr = tid >> 4;
    const int wf = (tid & 15) << 3;
    const float* gup_u = gup + (size_t)e * H_DIM * TWO_I + (f0 + wf);
    const float* gup_g = gup_u + I_DIM;

    const int tt = tid >> 4;
    const int tf = tid & 15;

    float accU[4][8], accG[4][8];
#pragma unroll
    for (int i = 0; i < 4; ++i)
#pragma unroll
        for (int j = 0; j < 8; ++j) { accU[i][j] = 0.f; accG[i][j] = 0.f; }

    for (int kb = 0; kb < H_DIM; kb += 16) {
        float4 av = make_float4(0.f, 0.f, 0.f, 0.f);
        if (atok >= 0) av = *(const float4*)(arow + kb + akq);
        sA[akq + 0][ar] = av.x * asc;
        sA[akq + 1][ar] = av.y * asc;
        sA[akq + 2][ar] = av.z * asc;
        sA[akq + 3][ar] = av.w * asc;

        const float* pu = gup_u + (size_t)(kb + wr) * TWO_I;
        const float* pg = gup_g + (size_t)(kb + wr) * TWO_I;
        float4 u0 = *(const float4*)(pu);
        float4 u1 = *(const float4*)(pu + 4);
        float4 g0 = *(const float4*)(pg);
        float4 g1 = *(const float4*)(pg + 4);
        *(float4*)&sWu[wr][wf]     = u0;
        *(float4*)&sWu[wr][wf + 4] = u1;
        *(float4*)&sWg[wr][wf]     = g0;
        *(float4*)&sWg[wr][wf + 4] = g1;
        __syncthreads();

#pragma unroll
        for (int k = 0; k < 16; ++k) {
            float4 a4  = *(const float4*)&sA[k][tt << 2];
            float4 bu0 = *(const float4*)&sWu[k][tf << 3];
            float4 bu1 = *(const float4*)&sWu[k][(tf << 3) + 4];
            float4 bg0 = *(const float4*)&sWg[k][tf << 3];
            float4 bg1 = *(const float4*)&sWg[k][(tf << 3) + 4];
            float aa[4] = {a4.x, a4.y, a4.z, a4.w};
            float bu[8] = {bu0.x, bu0.y, bu0.z, bu0.w, bu1.x, bu1.y, bu1.z, bu1.w};
            float bg[8] = {bg0.x, bg0.y, bg0.z, bg0.w, bg1.x, bg1.y, bg1.z, bg1.w};
#pragma unroll
            for (int i = 0; i < 4; ++i)
#pragma unroll
                for (int j = 0; j < 8; ++j) {
                    accU[i][j] = fmaf(aa[i], bu[j], accU[i][j]);
                    accG[i][j] = fmaf(aa[i], bg[j], accG[i][j]);
                }
        }
        __syncthreads();
    }

#pragma unroll
    for (int i = 0; i < 4; ++i) {
        int idx = t0 + (tt << 2) + i;
        if (idx >= cnt) continue;
        int tk = buckets[e * T_TOK + idx];
        float vals[8];
#pragma unroll
        for (int j = 0; j < 8; ++j) {
            float g = accG[i][j];
            float s = 1.f / (1.f + expf(-g));
            vals[j] = accU[i][j] * g * s;
        }
        float* orow = act + (size_t)tk * I_DIM + f0 + (tf << 3);
        *(float4*)orow       = make_float4(vals[0], vals[1], vals[2], vals[3]);
        *((float4*)orow + 1) = make_float4(vals[4], vals[5], vals[6], vals[7]);
    }
}

__global__ __launch_bounds__(256) void gemm2_kernel(
    const float* __restrict__ act, const float* __restrict__ dw,
    const int* __restrict__ counts, const int* __restrict__ buckets,
    float* __restrict__ out)
{
    __shared__ float sA[16][68];
    __shared__ float sW[16][132];

    const int tid = threadIdx.x;
    const int e   = blockIdx.x >> 6;
    const int t0  = (blockIdx.x & 63) << 6;
    const int cnt = counts[e];
    if (t0 >= cnt) return;
    const int f0 = blockIdx.y << 7;

    const int ar  = tid >> 2;
    const int akq = (tid & 3) << 2;
    const int aidx = t0 + ar;
    const int atok = (aidx < cnt) ? buckets[e * T_TOK + aidx] : -1;
    const float* arow = act + (size_t)(atok >= 0 ? atok : 0) * I_DIM;

    const int wr = tid >> 4;
    const int wf = (tid & 15) << 3;
    const float* dwb = dw + (size_t)e * I_DIM * H_DIM + (f0 + wf);

    const int tt = tid >> 4;
    const int tf = tid & 15;

    float acc[4][8];
#pragma unroll
    for (int i = 0; i < 4; ++i)
#pragma unroll
        for (int j = 0; j < 8; ++j) acc[i][j] = 0.f;

    for (int kb = 0; kb < I_DIM; kb += 16) {
        float4 av = make_float4(0.f, 0.f, 0.f, 0.f);
        if (atok >= 0) av = *(const float4*)(arow + kb + akq);
        sA[akq + 0][ar] = av.x;
        sA[akq + 1][ar] = av.y;
        sA[akq + 2][ar] = av.z;
        sA[akq + 3][ar] = av.w;

        const float* pw = dwb + (size_t)(kb + wr) * H_DIM;
        float4 w0 = *(const float4*)(pw);
        float4 w1 = *(const float4*)(pw + 4);
        *(float4*)&sW[wr][wf]     = w0;
        *(float4*)&sW[wr][wf + 4] = w1;
        __syncthreads();

#pragma unroll
        for (int k = 0; k < 16; ++k) {
            float4 a4 = *(const float4*)&sA[k][tt << 2];
            float4 b0 = *(const float4*)&sW[k][tf << 3];
            float4 b1 = *(const float4*)&sW[k][(tf << 3) + 4];
            float aa[4] = {a4.x, a4.y, a4.z, a4.w};
            float bb[8] = {b0.x, b0.y, b0.z, b0.w, b1.x, b1.y, b1.z, b1.w};
#pragma unroll
            for (int i = 0; i < 4; ++i)
#pragma unroll
                for (int j = 0; j < 8; ++j)
                    acc[i][j] = fmaf(aa[i], bb[j], acc[i][j]);
        }
        __syncthreads();
    }

#pragma unroll
    for (int i = 0; i < 4; ++i) {
        int idx = t0 + (tt << 2) + i;
        if (idx >= cnt) continue;
        int tk = buckets[e * T_TOK + idx];
        float* orow = out + (size_t)tk * H_DIM + f0 + (tf << 3);
        *(float4*)orow       = make_float4(acc[i][0], acc[i][1], acc[i][2], acc[i][3]);
        *((float4*)orow + 1) = make_float4(acc[i][4], acc[i][5], acc[i][6], acc[i][7]);
    }
}

extern "C" void kernel_launch(void* const* d_in, const int* in_sizes, int n_in,
                              void* d_out, int out_size, void* d_ws, size_t ws_size,
                              hipStream_t stream) {
    const float* x   = (const float*)d_in[0];
    const float* gw  = (const float*)d_in[1];
    const float* gup = (const float*)d_in[2];
    const float* dw  = (const float*)d_in[3];
    float* out = (float*)d_out;

    char* ws = (char*)d_ws;
    float* scale   = (float*)(ws + WS_SCALE);
    int*   counts  = (int*)(ws + WS_COUNTS);
    int*   buckets = (int*)(ws + WS_BUCKETS);

    hipMemsetAsync(counts, 0, E_NUM * sizeof(int), stream);
    router_kernel<<<T_TOK / 4, 256, 0, stream>>>(x, gw, scale, counts, buckets);

    if (ws_size >= WS_NEED_FAST) {
        short* xs  = (short*)(ws + WS_XS);
        __hip_bfloat16* act = (__hip_bfloat16*)(ws + WS_ACT);
        short* w1t = (short*)(ws + WS_W1T);
        short* w2t = (short*)(ws + WS_W2T);

        xs_kernel<<<T_TOK * H_DIM / 8 / 256, 256, 0, stream>>>(x, scale, xs);

        dim3 gt1(H_DIM / 64, TWO_I / 64, E_NUM);
        transpose_cvt_kernel<<<gt1, 256, 0, stream>>>(gup, w1t, H_DIM, TWO_I);
        dim3 gt2(I_DIM / 64, H_DIM / 64, E_NUM);
        transpose_cvt_kernel<<<gt2, 256, 0, stream>>>(dw, w2t, I_DIM, H_DIM);

        dim3 g1(E_NUM * 32, I_DIM / 64);
        gemm1_mfma_kernel<<<g1, 256, 0, stream>>>(xs, w1t, counts, buckets, act);

        dim3 g2(E_NUM * 32, H_DIM / 128);
        gemm2_mfma_kernel<<<g2, 256, 0, stream>>>(act, w2t, counts, buckets, out);
    } else {
        float* act = (float*)(ws + WS_ACT_OLD);
        dim3 g1(E_NUM * (T_TOK / 64), I_DIM / 128);
        gemm1_act_kernel<<<g1, 256, 0, stream>>>(x, gup, scale, counts, buckets, act);
        dim3 g2(E_NUM * (T_TOK / 64), H_DIM / 128);
        gemm2_kernel<<<g2, 256, 0, stream>>>(act, dw, counts, buckets, out);
    }
}

// Round 3
// 248.153 us; speedup vs baseline: 8.4588x; 2.5597x over previous
//
#include <hip/hip_runtime.h>
#include <hip/hip_bf16.h>
#include <cstddef>
#include <cstdint>

#define T_TOK 4096
#define H_DIM 2048
#define E_NUM 8
#define I_DIM 1024
#define TWO_I 2048
#define MROWS 5120      // worst-case 128-padded slot rows (4096 + 8*127 -> 5120)
#define MT    40        // MROWS/128 M-tiles

typedef __attribute__((ext_vector_type(8))) short bf16x8;
typedef __attribute__((ext_vector_type(4))) float f32x4;
typedef __attribute__((ext_vector_type(4))) int   i32x4;

// -------- workspace layout (bytes), total ~101.2 MB (ws proven >= 128 MB) ----
#define WS_SCALE   0            // f32[4096]
#define WS_COUNTS  16384        // int[8]
#define WS_OFFP    16448        // int[9]
#define WS_BUCKETS 16512        // int[8*4096]  ends 147584
#define WS_SLOTTOK 147584       // int[5120]    ends 168064
#define WS_XSG     (1u<<20)     // bf16[5120*2048] = 20.97 MB
#define WS_ACT     (23u<<20)    // bf16[5120*1024] = 10.49 MB
#define WS_WT      (34u<<20)    // shared w1t/w2t region, 67.11 MB -> ends ~101.2 MB

__device__ __forceinline__ short f2bf(float f) {
    uint32_t u = __builtin_bit_cast(uint32_t, f);
    u += 0x7fffu + ((u >> 16) & 1u);
    return (short)(u >> 16);
}

__device__ __forceinline__ void gload16(const void* g, void* l) {
    __builtin_amdgcn_global_load_lds(
        (const __attribute__((address_space(1))) void*)g,
        (__attribute__((address_space(3))) void*)l, 16, 0, 0);
}

// ---------------- router ----------------
__global__ __launch_bounds__(256) void router_kernel(
    const float* __restrict__ x, const float* __restrict__ gw,
    float* __restrict__ scale, int* __restrict__ counts, int* __restrict__ buckets)
{
    const int wid  = threadIdx.x >> 6;
    const int lane = threadIdx.x & 63;
    const int t = blockIdx.x * 4 + wid;
    if (t >= T_TOK) return;

    float acc[E_NUM];
#pragma unroll
    for (int e = 0; e < E_NUM; ++e) acc[e] = 0.f;

    const float* xr = x + (size_t)t * H_DIM;
    for (int h = lane; h < H_DIM; h += 64) {
        float xv = xr[h];
#pragma unroll
        for (int e = 0; e < E_NUM; ++e) acc[e] = fmaf(xv, gw[e * H_DIM + h], acc[e]);
    }
#pragma unroll
    for (int e = 0; e < E_NUM; ++e) {
        float v = acc[e];
#pragma unroll
        for (int off = 32; off > 0; off >>= 1) v += __shfl_xor(v, off);
        acc[e] = v;
    }
    if (lane == 0) {
        int best = 0; float bv = acc[0];
#pragma unroll
        for (int e = 1; e < E_NUM; ++e) { if (acc[e] > bv) { bv = acc[e]; best = e; } }
        scale[t] = 1.f / (1.f + expf(-bv));
        int pos = atomicAdd(&counts[best], 1);
        buckets[best * T_TOK + pos] = t;
    }
}

// ---------------- 128-padded prefix offsets ----------------
__global__ void offs_kernel(const int* __restrict__ counts, int* __restrict__ offP) {
    if (threadIdx.x == 0) {
        int run = 0;
#pragma unroll
        for (int e = 0; e < E_NUM; ++e) { offP[e] = run; run += (counts[e] + 127) & ~127; }
        offP[E_NUM] = run;
    }
}

// ---------------- gather: xsg[slot] = bf16(scale[tok] * x[tok]), slot_tok ----
__global__ __launch_bounds__(256) void gather_kernel(
    const float* __restrict__ x, const float* __restrict__ scale,
    const int* __restrict__ counts, const int* __restrict__ offP,
    const int* __restrict__ buckets, short* __restrict__ xsg,
    int* __restrict__ slot_tok)
{
    const int r = blockIdx.x;          // slot row 0..5119
    int e = 0;
#pragma unroll
    for (int k = 1; k < E_NUM; ++k) if (r >= offP[k]) e = k;
    const int pos = r - offP[e];
    const bool valid = (r < offP[E_NUM]) && (pos < counts[e]);
    const int tok = valid ? buckets[e * T_TOK + pos] : -1;
    if (threadIdx.x == 0) slot_tok[r] = tok;

    short* orow = xsg + (size_t)r * H_DIM + threadIdx.x * 8;
    if (!valid) {
        i32x4 z = {0, 0, 0, 0};
        *(i32x4*)orow = z;
        return;
    }
    const float sc = scale[tok];
    const float* xr = x + (size_t)tok * H_DIM + threadIdx.x * 8;
    float4 a = *(const float4*)xr;
    float4 b = *(const float4*)(xr + 4);
    short o[8] __attribute__((aligned(16)));
    o[0] = f2bf(a.x * sc); o[1] = f2bf(a.y * sc);
    o[2] = f2bf(a.z * sc); o[3] = f2bf(a.w * sc);
    o[4] = f2bf(b.x * sc); o[5] = f2bf(b.y * sc);
    o[6] = f2bf(b.z * sc); o[7] = f2bf(b.w * sc);
    *(i32x4*)orow = *(const i32x4*)o;
}

// ---------------- weight transpose + bf16 convert ----------------
// src: [E][K][N] f32  ->  dst: [E][N][K] bf16
__global__ __launch_bounds__(256) void transpose_cvt_kernel(
    const float* __restrict__ src, short* __restrict__ dst, int K, int N)
{
    __shared__ float s[64][65];
    const int e  = blockIdx.z;
    const int k0 = blockIdx.x * 64;
    const int n0 = blockIdx.y * 64;
    const int t  = threadIdx.x;

    const float* S = src + ((size_t)e * K + k0) * N + n0;
    const int kr = t >> 4, nc = (t & 15) * 4;
#pragma unroll
    for (int i = 0; i < 4; ++i) {
        float4 v = *(const float4*)(S + (size_t)(kr + i * 16) * N + nc);
        s[kr + i * 16][nc + 0] = v.x;
        s[kr + i * 16][nc + 1] = v.y;
        s[kr + i * 16][nc + 2] = v.z;
        s[kr + i * 16][nc + 3] = v.w;
    }
    __syncthreads();

    const int nr = t >> 2, kc = (t & 3) * 16;
    short tmp[16] __attribute__((aligned(16)));
#pragma unroll
    for (int j = 0; j < 16; ++j) tmp[j] = f2bf(s[kc + j][nr]);
    short* D = dst + ((size_t)e * N + n0 + nr) * K + k0 + kc;
    *(i32x4*)D       = *(const i32x4*)tmp;
    *(i32x4*)(D + 8) = *(const i32x4*)(tmp + 8);
}

// ---------------- grouped MFMA GEMM1 + SwiGLU (dense slots, dbuf prefetch) ----
// A = xsg rows m0..m0+127 (dense), B = w1t[e] rows {f0..f0+63, I+f0..I+f0+63}
// grid 640 = MT(40) x NT(16); consecutive logical wg share B panel; XCD swizzle
__global__ __launch_bounds__(256) void gemm1_mfma_kernel(
    const short* __restrict__ xsg, const short* __restrict__ w1t,
    const int* __restrict__ offP, short* __restrict__ act)
{
    __shared__ short sA[2][128 * 32];
    __shared__ short sB[2][128 * 32];

    const int bid = blockIdx.x;
    const int wg  = (bid & 7) * 80 + (bid >> 3);   // bijective: 640 % 8 == 0
    const int nt  = wg / MT;
    const int mt  = wg - nt * MT;
    const int m0  = mt << 7;
    if (m0 >= offP[E_NUM]) return;
    const int f0  = nt << 6;

    int e = 0;
#pragma unroll
    for (int k = 1; k < E_NUM; ++k) if (m0 >= offP[k]) e = k;

    const int tid = threadIdx.x, lane = tid & 63, w = tid >> 6;
    const int g = lane & 3, lr = lane >> 2;
    const int rA0 = (2 * w) * 16 + lr, rA1 = rA0 + 16;

    const short* srcA0 = xsg + (size_t)(m0 + rA0) * H_DIM + g * 8;
    const short* srcA1 = xsg + (size_t)(m0 + rA1) * H_DIM + g * 8;
    const int n0r = (rA0 < 64) ? (f0 + rA0) : (I_DIM + f0 + (rA0 & 63));
    const int n1r = (rA1 < 64) ? (f0 + rA1) : (I_DIM + f0 + (rA1 & 63));
    const short* srcB0 = w1t + ((size_t)e * TWO_I + n0r) * H_DIM + g * 8;
    const short* srcB1 = w1t + ((size_t)e * TWO_I + n1r) * H_DIM + g * 8;

    const int lm = lane & 15, lg8 = (lane >> 4) * 8;
    const int offA = (w * 32 + lm) * 32 + lg8;   // + mi*512
    const int offB = lm * 32 + lg8;              // + nf*512

    f32x4 acc[2][8];
#pragma unroll
    for (int i = 0; i < 2; ++i)
#pragma unroll
        for (int j = 0; j < 8; ++j) acc[i][j] = (f32x4){0.f, 0.f, 0.f, 0.f};

    auto STG = [&](int buf, int kb) {
        gload16(srcA0 + kb, &sA[buf][(2 * w) * 512]);
        gload16(srcA1 + kb, &sA[buf][(2 * w + 1) * 512]);
        gload16(srcB0 + kb, &sB[buf][(2 * w) * 512]);
        gload16(srcB1 + kb, &sB[buf][(2 * w + 1) * 512]);
    };
    auto CMP = [&](int buf) {
        const short* pA = &sA[buf][offA];
        const short* pB = &sB[buf][offB];
        bf16x8 a0 = *(const bf16x8*)pA;
        bf16x8 a1 = *(const bf16x8*)(pA + 512);
#pragma unroll
        for (int nf = 0; nf < 8; ++nf) {
            bf16x8 b = *(const bf16x8*)(pB + nf * 512);
            acc[0][nf] = __builtin_amdgcn_mfma_f32_16x16x32_bf16(a0, b, acc[0][nf], 0, 0, 0);
            acc[1][nf] = __builtin_amdgcn_mfma_f32_16x16x32_bf16(a1, b, acc[1][nf], 0, 0, 0);
        }
    };

    int cur = 0;
    STG(0, 0);
    for (int kb = 32; kb < H_DIM; kb += 32) {
        __syncthreads();          // drains vmcnt: staged cur is complete
        STG(cur ^ 1, kb);         // prefetch next tile (overlaps compute)
        CMP(cur);
        cur ^= 1;
    }
    __syncthreads();
    CMP(cur);

    // epilogue: act[slot] = up * gate * sigmoid(gate)
    const int rbase = w * 32 + (lane >> 4) * 4;
#pragma unroll
    for (int mi = 0; mi < 2; ++mi) {
#pragma unroll
        for (int rr = 0; rr < 4; ++rr) {
            const int row = rbase + mi * 16 + rr;
            short* orow = act + (size_t)(m0 + row) * I_DIM + f0 + lm;
#pragma unroll
            for (int nf = 0; nf < 4; ++nf) {
                float up = acc[mi][nf][rr];
                float gt = acc[mi][nf + 4][rr];
                float v  = up * gt / (1.f + expf(-gt));
                orow[nf * 16] = f2bf(v);
            }
        }
    }
}

// ---------------- grouped MFMA GEMM2 (dense slots -> scatter out) ----------
__global__ __launch_bounds__(256) void gemm2_mfma_kernel(
    const short* __restrict__ act, const short* __restrict__ w2t,
    const int* __restrict__ offP, const int* __restrict__ slot_tok,
    float* __restrict__ out)
{
    __shared__ short sA[2][128 * 32];
    __shared__ short sB[2][128 * 32];
    __shared__ int   sTok[128];

    const int bid = blockIdx.x;
    const int wg  = (bid & 7) * 80 + (bid >> 3);
    const int nt  = wg / MT;
    const int mt  = wg - nt * MT;
    const int m0  = mt << 7;
    if (m0 >= offP[E_NUM]) return;
    const int h0  = nt << 7;

    int e = 0;
#pragma unroll
    for (int k = 1; k < E_NUM; ++k) if (m0 >= offP[k]) e = k;

    const int tid = threadIdx.x, lane = tid & 63, w = tid >> 6;
    if (tid < 128) sTok[tid] = slot_tok[m0 + tid];

    const int g = lane & 3, lr = lane >> 2;
    const int rA0 = (2 * w) * 16 + lr, rA1 = rA0 + 16;

    const short* srcA0 = act + (size_t)(m0 + rA0) * I_DIM + g * 8;
    const short* srcA1 = act + (size_t)(m0 + rA1) * I_DIM + g * 8;
    const short* srcB0 = w2t + ((size_t)e * H_DIM + h0 + rA0) * I_DIM + g * 8;
    const short* srcB1 = w2t + ((size_t)e * H_DIM + h0 + rA1) * I_DIM + g * 8;

    const int lm = lane & 15, lg8 = (lane >> 4) * 8;
    const int offA = (w * 32 + lm) * 32 + lg8;
    const int offB = lm * 32 + lg8;

    f32x4 acc[2][8];
#pragma unroll
    for (int i = 0; i < 2; ++i)
#pragma unroll
        for (int j = 0; j < 8; ++j) acc[i][j] = (f32x4){0.f, 0.f, 0.f, 0.f};

    auto STG = [&](int buf, int kb) {
        gload16(srcA0 + kb, &sA[buf][(2 * w) * 512]);
        gload16(srcA1 + kb, &sA[buf][(2 * w + 1) * 512]);
        gload16(srcB0 + kb, &sB[buf][(2 * w) * 512]);
        gload16(srcB1 + kb, &sB[buf][(2 * w + 1) * 512]);
    };
    auto CMP = [&](int buf) {
        const short* pA = &sA[buf][offA];
        const short* pB = &sB[buf][offB];
        bf16x8 a0 = *(const bf16x8*)pA;
        bf16x8 a1 = *(const bf16x8*)(pA + 512);
#pragma unroll
        for (int nf = 0; nf < 8; ++nf) {
            bf16x8 b = *(const bf16x8*)(pB + nf * 512);
            acc[0][nf] = __builtin_amdgcn_mfma_f32_16x16x32_bf16(a0, b, acc[0][nf], 0, 0, 0);
            acc[1][nf] = __builtin_amdgcn_mfma_f32_16x16x32_bf16(a1, b, acc[1][nf], 0, 0, 0);
        }
    };

    int cur = 0;
    STG(0, 0);
    for (int kb = 32; kb < I_DIM; kb += 32) {
        __syncthreads();
        STG(cur ^ 1, kb);
        CMP(cur);
        cur ^= 1;
    }
    __syncthreads();
    CMP(cur);

    const int rbase = w * 32 + (lane >> 4) * 4;
#pragma unroll
    for (int mi = 0; mi < 2; ++mi) {
#pragma unroll
        for (int rr = 0; rr < 4; ++rr) {
            const int row = rbase + mi * 16 + rr;
            const int tok = sTok[row];
            if (tok < 0) continue;
            float* orow = out + (size_t)tok * H_DIM + h0 + lm;
#pragma unroll
            for (int nf = 0; nf < 8; ++nf) orow[nf * 16] = acc[mi][nf][rr];
        }
    }
}

extern "C" void kernel_launch(void* const* d_in, const int* in_sizes, int n_in,
                              void* d_out, int out_size, void* d_ws, size_t ws_size,
                              hipStream_t stream) {
    const float* x   = (const float*)d_in[0];
    const float* gw  = (const float*)d_in[1];
    const float* gup = (const float*)d_in[2];
    const float* dw  = (const float*)d_in[3];
    float* out = (float*)d_out;

    char* ws = (char*)d_ws;
    float* scale    = (float*)(ws + WS_SCALE);
    int*   counts   = (int*)(ws + WS_COUNTS);
    int*   offP     = (int*)(ws + WS_OFFP);
    int*   buckets  = (int*)(ws + WS_BUCKETS);
    int*   slot_tok = (int*)(ws + WS_SLOTTOK);
    short* xsg      = (short*)(ws + WS_XSG);
    short* act      = (short*)(ws + WS_ACT);
    short* wt       = (short*)(ws + WS_WT);    // shared: w1t then w2t

    hipMemsetAsync(counts, 0, E_NUM * sizeof(int), stream);
    router_kernel<<<T_TOK / 4, 256, 0, stream>>>(x, gw, scale, counts, buckets);
    offs_kernel<<<1, 64, 0, stream>>>(counts, offP);
    gather_kernel<<<MROWS, 256, 0, stream>>>(x, scale, counts, offP, buckets, xsg, slot_tok);

    // w1t = transpose(gate_up_weight) as bf16, then GEMM1
    dim3 gt1(H_DIM / 64, TWO_I / 64, E_NUM);
    transpose_cvt_kernel<<<gt1, 256, 0, stream>>>(gup, wt, H_DIM, TWO_I);
    gemm1_mfma_kernel<<<MT * 16, 256, 0, stream>>>(xsg, wt, offP, act);

    // w2t = transpose(down_weight) as bf16 (reuses region), then GEMM2
    dim3 gt2(I_DIM / 64, H_DIM / 64, E_NUM);
    transpose_cvt_kernel<<<gt2, 256, 0, stream>>>(dw, wt, I_DIM, H_DIM);
    gemm2_mfma_kernel<<<MT * 16, 256, 0, stream>>>(act, wt, offP, slot_tok, out);
}